// Round 14
// baseline (1432.682 us; speedup 1.0000x reference)
//
#include <hip/hip_runtime.h>
#include <stdint.h>

// Net_11587821765063: sequential SNN scan, T=1000 steps.
// Output = spike_out (T,1,COUT) float32 only; w / traces are not returned.
//
// Math reductions (absmax 0 in rounds 1-13):
//  - potentiation p[t][i] = 2 if x[t][i] else (1 if (t==0 or x[t-1][i]) else 0)
//  - depression for row o at t = -x[t][i] iff (!spike[t][o] && spike[t-1][o]),
//    spike[-1] := true (cout init quirk).
//  - prohibit P[t] = 1 iff any spike at t-1 (grid-wide 1-bit OR); P[0]=0.
//
// Round 14: BARRIER-FREE single-wave blocks + selfdec.
// r13's residual ~1800 cyc/step = 4-wave barrier + LDS round trip + skew +
// shuffle chains. With r12's OR short-circuit (own rows spiked at u-2 =>
// P[u-1]=1, ~98%+ of steps) a block needs no cross-wave communication at
// all. Structure: 256 blocks x 64 threads (1 wave), 2 rows/wave, 13
// cols/lane. Block hb = OR of its own 2 rows, in-register. Publish = one
// byte-store (0xB0|hb) into a 256 B/step table; fallback gather = one
// dword/lane (rare). No LDS, no __syncthreads, no vmcnt drains.
// FP cores reused verbatim: r5 fold4 (2 rows x 2 branches - exactly this
// case), r7 fold2 for all-eq (bit-identical per-sum tree: fold4 with
// dB_r==dA_r reduces to it stage-by-stage), r13 branchy updates + out-bit
// batching. 2-step speculation recurrence unchanged.

#define T_STEPS 1000
#define CIN     784
#define COUT    512
#define CPL     13            // columns per lane (64*13 = 832 >= 784)
#define NBLK    256           // single-wave blocks, 2 rows each
#define VTHR_F   12500.0f
#define PROHIB_F 11250.0f

#define SLOTS_BYTES (T_STEPS * NBLK)          // 1 byte per (u, blk) = 256000
#define CODE_OFFSET 524288                    // 512 KiB >= 256000 B of slots

// ---- prep: zero slot bytes and pack per-(t,lane) 16-byte code slot:
// byte j (j<13) encodes col = lane*13+j: bit0 = x[t][col], bits[2:1] = p.
__global__ __launch_bounds__(256) void prep_kernel(const int* __restrict__ x,
                                                   uint8_t* __restrict__ code,
                                                   uint32_t* __restrict__ slots32) {
    int gid = blockIdx.x * blockDim.x + threadIdx.x;   // one per (t, lane)
    if (gid >= T_STEPS * 64) return;
    slots32[gid] = 0u;                                 // 64000 x 4B = 256000 B
    int t = gid >> 6;
    int lane = gid & 63;
    uint32_t wds[4] = {0u, 0u, 0u, 0u};
    #pragma unroll
    for (int j = 0; j < CPL; ++j) {
        int col = lane * CPL + j;
        uint32_t b = 0u;
        if (col < CIN) {
            int xc = x[t * CIN + col];
            int xp = (t > 0) ? x[(t - 1) * CIN + col] : 0;
            int p = xc ? 2 : ((t == 0) ? 1 : (xp ? 1 : 0));
            b = (uint32_t)((xc & 1) | (p << 1));
        }
        wds[j >> 2] |= b << ((j & 3) * 8);
    }
    ((uint4*)code)[gid] = make_uint4(wds[0], wds[1], wds[2], wds[3]);
}

__device__ __forceinline__ int rfl(bool b) {      // force SGPR / s_cbranch
    return __builtin_amdgcn_readfirstlane(b ? 1 : 0);
}

__global__ __launch_bounds__(64, 1) void snn_kernel(const float* __restrict__ weight,
                                                    const uint8_t* __restrict__ code,
                                                    uint8_t* __restrict__ slots,
                                                    float* __restrict__ out) {
    const int lane = threadIdx.x;          // one wave per block
    const int blk  = blockIdx.x;
    const int row0 = blk * 2;              // 2 consecutive rows

    float wA0[CPL], wA1[CPL], wB0[CPL], wB1[CPL];
    #pragma unroll
    for (int j = 0; j < CPL; ++j) {
        int col = lane * CPL + j;
        bool in = (col < CIN);
        float v0 = in ? weight[(row0 + 0) * CIN + col] : 0.0f;
        float v1 = in ? weight[(row0 + 1) * CIN + col] : 0.0f;
        wA0[j] = v0; wB0[j] = v0;
        wA1[j] = v1; wB1[j] = v1;
    }

    const uint4* code4 = (const uint4*)code;
    uint4 cw  = code4[lane];               // codes for u=0
    uint4 cwn = code4[64 + lane];          // codes for u=1 (prefetch)

    float memA0 = 0, memA1 = 0, memB0 = 0, memB1 = 0;
    bool psA0 = true, psA1 = true, psB0 = true, psB1 = true;  // spike(-1)=true
    bool eq0 = true, eq1 = true;           // wB==wA per row
    int p2 = 0, p3 = 0;                    // actual P[u-2], P[u-3]
    int hh_m1 = 0, hh_m2 = 0;              // own hb(u-1), hb(u-2)
    uint32_t myb0 = 0u, myb1 = 0u;         // out bits: step v when v%64==lane

    for (int u = 0; u < T_STEPS; ++u) {
        // ---- top-of-loop issues: code load for u+2, gated gather for u-2 ----
        uint4 cw2 = (u + 2 < T_STEPS) ? code4[(size_t)(u + 2) * 64 + lane]
                                      : make_uint4(0u, 0u, 0u, 0u);
        const int kk = (p3 << 1) | p2;                 // (P[u-3]<<1)|P[u-2]
        const bool selfdec = (u >= 2) && (((hh_m2 >> kk) & 1) != 0);
        const uint32_t* gl =
            (const uint32_t*)(slots + (size_t)(u >= 2 ? u - 2 : 0) * NBLK);
        uint32_t gv = 0xB0B0B0B0u;                     // sentinel-passing dummy
        if (u >= 2 && !selfdec)
            gv = __hip_atomic_load(&gl[lane], __ATOMIC_RELAXED,
                                   __HIP_MEMORY_SCOPE_AGENT);

        // ---- decode x bits for step u; A-dots (2 rows) ----
        uint32_t cwd[4] = {cw.x, cw.y, cw.z, cw.w};
        float xf[CPL];
        #pragma unroll
        for (int j = 0; j < CPL; ++j)
            xf[j] = (float)((cwd[j >> 2] >> ((j & 3) * 8)) & 1u);
        float dA0 = 0.0f, dA1 = 0.0f;
        #pragma unroll
        for (int j = 0; j < CPL; ++j) {
            dA0 += xf[j] * wA0[j];         // exact: x in {0,1}
            dA1 += xf[j] * wA1[j];
        }

        float dotA0, dotA1, dotB0, dotB1;
        if (rfl(eq0 && eq1)) {
            // fold2 (r7, validated): per-sum tree identical to fold4 with
            // dB_r == dA_r
            bool hi = (lane & 32) != 0;
            float k0 = hi ? dA1 : dA0;
            float s0 = hi ? dA0 : dA1;
            k0 += __shfl_xor(s0, 32, 64);
            k0 += __shfl_xor(k0, 16, 64);
            k0 += __shfl_xor(k0, 8, 64);
            k0 += __shfl_xor(k0, 4, 64);
            k0 += __shfl_xor(k0, 2, 64);
            k0 += __shfl_xor(k0, 1, 64);
            float ot = __shfl_xor(k0, 32, 64);
            dotA0 = hi ? ot : k0;
            dotA1 = hi ? k0 : ot;
            dotB0 = dotA0; dotB1 = dotA1;
        } else {
            float dB0 = dA0, dB1 = dA1;    // eq rows feed dA (bit-identical)
            if (!rfl(eq0)) { dB0 = 0.0f;
                #pragma unroll
                for (int j = 0; j < CPL; ++j) dB0 += xf[j] * wB0[j]; }
            if (!rfl(eq1)) { dB1 = 0.0f;
                #pragma unroll
                for (int j = 0; j < CPL; ++j) dB1 += xf[j] * wB1[j]; }
            // fold4 (r5, validated: built for exactly 2 rows x 2 branches)
            bool half = (lane & 32) != 0;
            float kx = half ? dB0 : dA0;
            float ky = half ? dB1 : dA1;
            float sx = half ? dA0 : dB0;
            float sy = half ? dA1 : dB1;
            kx += __shfl_xor(sx, 32, 64);
            ky += __shfl_xor(sy, 32, 64);
            bool subq = (lane & 16) != 0;
            float kq = subq ? ky : kx;
            float ss = subq ? kx : ky;
            kq += __shfl_xor(ss, 16, 64);
            kq += __shfl_xor(kq, 8, 64);
            kq += __shfl_xor(kq, 4, 64);
            kq += __shfl_xor(kq, 2, 64);
            kq += __shfl_xor(kq, 1, 64);
            float b1 = __shfl_xor(kq, 16, 64);
            float b2 = __shfl_xor(kq, 32, 64);
            float b3 = __shfl_xor(b1, 32, 64);
            int q = lane >> 4;
            dotA0 = (q == 0) ? kq : (q == 1) ? b1 : (q == 2) ? b2 : b3;
            dotA1 = (q == 0) ? b1 : (q == 1) ? kq : (q == 2) ? b3 : b2;
            dotB0 = (q == 0) ? b2 : (q == 1) ? b3 : (q == 2) ? kq : b1;
            dotB1 = (q == 0) ? b3 : (q == 1) ? b2 : (q == 2) ? b1 : kq;
        }

        // ---- 4 hypotheses per row (d = P[u-1] branch, c = P[u] branch) ----
#define HYP(R)                                                                \
        float sa##R = memA##R + dotA##R;                                      \
        float sb##R = memB##R + dotB##R;                                      \
        float m00_##R = fmaxf(sa##R, 0.0f);                                   \
        float m01_##R = fmaxf(sa##R - PROHIB_F, 0.0f);                        \
        float m10_##R = fmaxf(sb##R, 0.0f);                                   \
        float m11_##R = fmaxf(sb##R - PROHIB_F, 0.0f);                        \
        bool s00_##R = m00_##R >= VTHR_F;                                     \
        bool s01_##R = m01_##R >= VTHR_F;                                     \
        bool s10_##R = m10_##R >= VTHR_F;                                     \
        bool s11_##R = m11_##R >= VTHR_F;
        HYP(0) HYP(1)
#undef HYP
        int hb = ((s00_0 || s00_1) ? 1 : 0) | ((s01_0 || s01_1) ? 2 : 0) |
                 ((s10_0 || s10_1) ? 4 : 0) | ((s11_0 || s11_1) ? 8 : 0);

        // ---- publish hb(u) immediately (fire-and-forget byte store) ----
        if (lane == 0)
            __hip_atomic_store(&slots[(size_t)u * NBLK + blk],
                               (uint8_t)(0xB0u | (uint32_t)hb),
                               __ATOMIC_RELAXED, __HIP_MEMORY_SCOPE_AGENT);

        // ---- resolve P[u-1]: self-decide (common) or global fallback ----
        int bst = 0;
        if (u >= 2) {
            if (selfdec) {
                bst = 1;                   // own rows spiked at u-2
            } else {
                for (;;) {
                    uint32_t tm = (gv & 0xF0F0F0F0u) ^ 0xB0B0B0B0u;
                    uint32_t bb = (gv >> kk) & 0x01010101u;
                    bool anyset = false, allp = true;
                    #pragma unroll
                    for (int i = 0; i < 4; ++i) {
                        bool p = ((tm >> (8 * i)) & 0xFFu) == 0u;
                        allp = allp && p;
                        anyset = anyset || (p && (((bb >> (8 * i)) & 1u) != 0u));
                    }
                    if (__any((int)anyset)) { bst = 1; break; }
                    if (__all((int)allp)) {
                        bst = __any((int)(bb != 0u));
                        break;
                    }
                    __builtin_amdgcn_s_sleep(1);       // backoff (rare path)
                    gv = __hip_atomic_load(&gl[lane], __ATOMIC_RELAXED,
                                           __HIP_MEMORY_SCOPE_AGENT);
                }
            }
        }
        p3 = p2; p2 = bst;
        hh_m2 = hh_m1; hh_m1 = hb;

        // ---- per-row: collapse d=bst, record out bit, new membranes ----
#define TAIL(R)                                                               \
        bool sprv##R = bst ? psB##R : psA##R;                                 \
        bool sc0_##R = bst ? s10_##R : s00_##R;                               \
        bool sc1_##R = bst ? s11_##R : s01_##R;                               \
        float mc0_##R = bst ? m10_##R : m00_##R;                              \
        float mc1_##R = bst ? m11_##R : m01_##R;                              \
        memA##R = sc0_##R ? 0.0f : mc0_##R;                                   \
        memB##R = sc1_##R ? 0.0f : mc1_##R;                                   \
        bool eqN##R = (sc0_##R == sc1_##R) && (memA##R == memB##R);
        TAIL(0) TAIL(1)
#undef TAIL

        if (u >= 1) {
            int v = u - 1;
            if ((v & 63) == lane) {
                myb0 |= (sprv0 ? 1u : 0u) << (v >> 6);
                myb1 |= (sprv1 ? 1u : 0u) << (v >> 6);
            }
        }

        // ---- weight updates: wave-uniform branches, only taken path issues
        auto upd = [&](float (&wAr)[CPL], float (&wBr)[CPL], bool& eqR,
                       bool sc0, bool sc1, bool sprv, bool eqN) {
            if (rfl((bst != 0) && !eqR)) {             // collapse to d-branch
                #pragma unroll
                for (int j = 0; j < CPL; ++j) wAr[j] = wBr[j];
            }
            if (rfl(eqN)) {
                if (rfl(sc0)) {                        // potentiate (common)
                    #pragma unroll
                    for (int j = 0; j < CPL; ++j) {
                        float pfj = (float)((cwd[j >> 2] >> ((j & 3) * 8 + 1)) & 3u);
                        wAr[j] = fminf(wAr[j] + pfj, 127.0f);
                    }
                } else if (rfl(sprv)) {                // depress
                    #pragma unroll
                    for (int j = 0; j < CPL; ++j)
                        wAr[j] = fmaxf(wAr[j] - xf[j], 0.0f);
                }
                // wB stale; eq flag covers it
            } else {
                if (rfl(sc1)) {                        // c=1 into wB (from base)
                    #pragma unroll
                    for (int j = 0; j < CPL; ++j) {
                        float pfj = (float)((cwd[j >> 2] >> ((j & 3) * 8 + 1)) & 3u);
                        wBr[j] = fminf(wAr[j] + pfj, 127.0f);
                    }
                } else if (rfl(sprv)) {
                    #pragma unroll
                    for (int j = 0; j < CPL; ++j)
                        wBr[j] = fmaxf(wAr[j] - xf[j], 0.0f);
                } else {
                    #pragma unroll
                    for (int j = 0; j < CPL; ++j) wBr[j] = wAr[j];
                }
                if (rfl(sc0)) {                        // c=0 in place
                    #pragma unroll
                    for (int j = 0; j < CPL; ++j) {
                        float pfj = (float)((cwd[j >> 2] >> ((j & 3) * 8 + 1)) & 3u);
                        wAr[j] = fminf(wAr[j] + pfj, 127.0f);
                    }
                } else if (rfl(sprv)) {
                    #pragma unroll
                    for (int j = 0; j < CPL; ++j)
                        wAr[j] = fmaxf(wAr[j] - xf[j], 0.0f);
                }
            }
            eqR = eqN;
        };
        upd(wA0, wB0, eq0, sc0_0, sc1_0, sprv0, eqN0);
        upd(wA1, wB1, eq1, sc0_1, sc1_1, sprv1, eqN1);
        psA0 = sc0_0; psA1 = sc0_1;
        psB0 = sc1_0; psB1 = sc1_1;

        cw = cwn; cwn = cw2;
    }

    // ---- epilogue: resolve P[T-1], record last bits, write all outputs ----
    {
        const int kk = (p3 << 1) | p2;
        int cst;
        if (((hh_m2 >> kk) & 1) != 0) {
            cst = 1;                       // own rows forced the OR
        } else {
            const uint32_t* gl2 =
                (const uint32_t*)(slots + (size_t)(T_STEPS - 2) * NBLK);
            uint32_t gv2;
            for (;;) {
                gv2 = __hip_atomic_load(&gl2[lane], __ATOMIC_RELAXED,
                                        __HIP_MEMORY_SCOPE_AGENT);
                uint32_t tm = (gv2 & 0xF0F0F0F0u) ^ 0xB0B0B0B0u;
                uint32_t bb = (gv2 >> kk) & 0x01010101u;
                bool anyset = false, allp = true;
                #pragma unroll
                for (int i = 0; i < 4; ++i) {
                    bool p = ((tm >> (8 * i)) & 0xFFu) == 0u;
                    allp = allp && p;
                    anyset = anyset || (p && (((bb >> (8 * i)) & 1u) != 0u));
                }
                if (__any((int)anyset)) { cst = 1; break; }
                if (__all((int)allp)) { cst = __any((int)(bb != 0u)); break; }
                __builtin_amdgcn_s_sleep(1);
            }
        }
        bool sr0 = cst ? psB0 : psA0;
        bool sr1 = cst ? psB1 : psA1;
        {
            int v = T_STEPS - 1;
            if ((v & 63) == lane) {
                myb0 |= (sr0 ? 1u : 0u) << (v >> 6);
                myb1 |= (sr1 ? 1u : 0u) << (v >> 6);
            }
        }
        // write both rows' 1000 spike floats from the bit registers
        #pragma unroll
        for (int b = 0; b < 16; ++b) {
            int s = b * 64 + lane;
            if (s < T_STEPS) {
                float2 v2 = make_float2((float)((myb0 >> b) & 1u),
                                        (float)((myb1 >> b) & 1u));
                *(float2*)(out + (size_t)s * COUT + row0) = v2;
            }
        }
    }
}

extern "C" void kernel_launch(void* const* d_in, const int* in_sizes, int n_in,
                              void* d_out, int out_size, void* d_ws, size_t ws_size,
                              hipStream_t stream) {
    const int*   x      = (const int*)d_in[0];     // (T,1,CIN) int32
    const float* weight = (const float*)d_in[1];   // (COUT,CIN) f32
    float* out = (float*)d_out;                    // (T,1,COUT) f32

    uint8_t* slots = (uint8_t*)d_ws;
    uint8_t* code  = (uint8_t*)d_ws + CODE_OFFSET;

    int prep_threads = T_STEPS * 64;
    prep_kernel<<<(prep_threads + 255) / 256, 256, 0, stream>>>(x, code,
                                                                (uint32_t*)slots);
    snn_kernel<<<NBLK, 64, 0, stream>>>(weight, code, slots, out);
}

// Round 15
// 1155.030 us; speedup vs baseline: 1.2404x; 1.2404x over previous
//
#include <hip/hip_runtime.h>
#include <stdint.h>

// Net_11587821765063: sequential SNN scan, T=1000 steps.
// Output = spike_out (T,1,COUT) float32 only; w / traces are not returned.
//
// Math reductions (absmax 0 in rounds 1-14):
//  - potentiation p[t][i] = 2 if x[t][i] else (1 if (t==0 or x[t-1][i]) else 0)
//  - depression for row o at t = -x[t][i] iff (!spike[t][o] && spike[t-1][o]),
//    spike[-1] := true (cout init quirk).
//  - prohibit P[t] = 1 iff any spike at t-1 (grid-wide 1-bit OR); P[0]=0.
//
// Round 15: FULLY AUTONOMOUS 1-ROW WAVES. The selfdec argument (r12) applies
// per-row, not just per-block: P[u-1] = OR of all rows' spike(u-2); a wave's
// OWN row spikes ~88% of steps, so own-hb selfdec resolves P with no LDS,
// no barrier, no gather. 12% fallback reads the global per-row byte table
// (512 B/step) and short-circuits on the FIRST present byte with bit kk set
// (P=1 virtually always => first-arrival wait, never last-arrival; full
// sentinel wait only when the true OR is 0 ~ never).
// Structure: 128 blocks x 256 thr = 512 autonomous waves, 1 row/wave
// (r7-proven thinnest), 1 wave/SIMD. No __syncthreads anywhere -> code
// prefetch genuinely spans 2 iterations; publish stores never drained.
// FP cores verbatim from validated rounds: 13-FMA dot order (r1+), 6-stage
// eq butterfly (r13), 7-op fold2 non-eq (r7), branchy updates (r7/r12/r13),
// out-bit batching (r13). 2-step speculation recurrence unchanged.

#define T_STEPS 1000
#define CIN     784
#define COUT    512
#define CPL     13            // columns per lane (64*13 = 832 >= 784)
#define NROW    512           // one publish byte per row per step
#define VTHR_F   12500.0f
#define PROHIB_F 11250.0f

#define SLOTS_BYTES (T_STEPS * NROW)          // 512000 B
#define CODE_OFFSET 524288                    // 512 KiB >= 512000 B of slots

// ---- prep: zero slot bytes and pack per-(t,lane) 16-byte code slot:
// byte j (j<13) encodes col = lane*13+j: bit0 = x[t][col], bits[2:1] = p.
__global__ __launch_bounds__(256) void prep_kernel(const int* __restrict__ x,
                                                   uint8_t* __restrict__ code,
                                                   uint2* __restrict__ slots2) {
    int gid = blockIdx.x * blockDim.x + threadIdx.x;   // one per (t, lane)
    if (gid >= T_STEPS * 64) return;
    slots2[gid] = make_uint2(0u, 0u);                  // 64000 x 8B = 512000 B
    int t = gid >> 6;
    int lane = gid & 63;
    uint32_t wds[4] = {0u, 0u, 0u, 0u};
    #pragma unroll
    for (int j = 0; j < CPL; ++j) {
        int col = lane * CPL + j;
        uint32_t b = 0u;
        if (col < CIN) {
            int xc = x[t * CIN + col];
            int xp = (t > 0) ? x[(t - 1) * CIN + col] : 0;
            int p = xc ? 2 : ((t == 0) ? 1 : (xp ? 1 : 0));
            b = (uint32_t)((xc & 1) | (p << 1));
        }
        wds[j >> 2] |= b << ((j & 3) * 8);
    }
    ((uint4*)code)[gid] = make_uint4(wds[0], wds[1], wds[2], wds[3]);
}

__device__ __forceinline__ int rfl(bool b) {      // force SGPR / s_cbranch
    return __builtin_amdgcn_readfirstlane(b ? 1 : 0);
}

// scan one gathered uint64 (8 row-bytes): present = high nibble 0xB;
// set = present && hypothesis bit kk. Returns via out-params.
__device__ __forceinline__ void scan8(unsigned long long gv, int kk,
                                      bool& anyset, bool& allp) {
    anyset = false; allp = true;
    #pragma unroll
    for (int i = 0; i < 8; ++i) {
        uint32_t b = (uint32_t)(gv >> (8 * i)) & 0xFFu;
        bool p = (b & 0xF0u) == 0xB0u;
        allp = allp && p;
        anyset = anyset || (p && (((b >> kk) & 1u) != 0u));
    }
}

__global__ __launch_bounds__(256, 1) void snn_kernel(const float* __restrict__ weight,
                                                     const uint8_t* __restrict__ code,
                                                     uint8_t* __restrict__ slots,
                                                     float* __restrict__ out) {
    const int tid  = threadIdx.x;
    const int wave = tid >> 6;
    const int lane = tid & 63;
    const int row  = blockIdx.x * 4 + wave;    // 512 autonomous waves

    float wA[CPL], wB[CPL];
    #pragma unroll
    for (int j = 0; j < CPL; ++j) {
        int col = lane * CPL + j;
        float v = (col < CIN) ? weight[row * CIN + col] : 0.0f;
        wA[j] = v; wB[j] = v;
    }

    const uint4* code4 = (const uint4*)code;
    uint4 cw  = code4[lane];               // codes for u=0
    uint4 cwn = code4[64 + lane];          // codes for u=1 (prefetch)

    float memA = 0.0f, memB = 0.0f;
    bool  psA = true, psB = true;          // spike(-1)=true quirk
    bool  eq  = true;                      // wB == wA (and memB==memA, psB==psA)
    int p2 = 0, p3 = 0;                    // actual P[u-2], P[u-3]
    int hb_m1 = 0, hb_m2 = 0;              // own row hb(u-1), hb(u-2)
    uint32_t myb = 0u;                     // out bits: step v when v%64==lane

    for (int u = 0; u < T_STEPS; ++u) {
        // ---- top-of-loop issues: code load for u+2, gated gather for u-2 ----
        uint4 cw2 = (u + 2 < T_STEPS) ? code4[(size_t)(u + 2) * 64 + lane]
                                      : make_uint4(0u, 0u, 0u, 0u);
        const int kk = (p3 << 1) | p2;                 // (P[u-3]<<1)|P[u-2]
        const bool selfdec = (u >= 2) && (((hb_m2 >> kk) & 1) != 0);
        const unsigned long long* gl =
            (const unsigned long long*)(slots + (size_t)(u >= 2 ? u - 2 : 0) * NROW);
        unsigned long long gv = 0xB0B0B0B0B0B0B0B0ull; // sentinel-passing dummy
        if (u >= 2 && !rfl(selfdec))
            gv = __hip_atomic_load(&gl[lane], __ATOMIC_RELAXED,
                                   __HIP_MEMORY_SCOPE_AGENT);

        // ---- decode x bits for step u; dot(s) ----
        uint32_t cwd[4] = {cw.x, cw.y, cw.z, cw.w};
        float xf[CPL];
        #pragma unroll
        for (int j = 0; j < CPL; ++j)
            xf[j] = (float)((cwd[j >> 2] >> ((j & 3) * 8)) & 1u);
        float dA = 0.0f;
        #pragma unroll
        for (int j = 0; j < CPL; ++j) dA += xf[j] * wA[j];   // exact: x in {0,1}

        float dotA, dotB;
        if (rfl(eq)) {
            // 6-stage butterfly (r13 eq-case, validated)
            float k0 = dA;
            k0 += __shfl_xor(k0, 32, 64);
            k0 += __shfl_xor(k0, 16, 64);
            k0 += __shfl_xor(k0, 8, 64);
            k0 += __shfl_xor(k0, 4, 64);
            k0 += __shfl_xor(k0, 2, 64);
            k0 += __shfl_xor(k0, 1, 64);
            dotA = k0; dotB = k0;
        } else {
            float dB = 0.0f;
            #pragma unroll
            for (int j = 0; j < CPL; ++j) dB += xf[j] * wB[j];
            // 7-op fold2 (r7, validated)
            bool hi = (lane & 32) != 0;
            float k0 = hi ? dB : dA;
            float s0 = hi ? dA : dB;
            k0 += __shfl_xor(s0, 32, 64);
            k0 += __shfl_xor(k0, 16, 64);
            k0 += __shfl_xor(k0, 8, 64);
            k0 += __shfl_xor(k0, 4, 64);
            k0 += __shfl_xor(k0, 2, 64);
            k0 += __shfl_xor(k0, 1, 64);
            float ot = __shfl_xor(k0, 32, 64);
            dotA = hi ? ot : k0;
            dotB = hi ? k0 : ot;
        }

        // ---- 4 hypotheses (d = P[u-1] branch, c = P[u] branch) ----
        float sa = memA + dotA;            // reference op order
        float sb = memB + dotB;
        float m00 = fmaxf(sa, 0.0f),            m01 = fmaxf(sa - PROHIB_F, 0.0f);
        float m10 = fmaxf(sb, 0.0f),            m11 = fmaxf(sb - PROHIB_F, 0.0f);
        bool s00 = m00 >= VTHR_F, s01 = m01 >= VTHR_F;
        bool s10 = m10 >= VTHR_F, s11 = m11 >= VTHR_F;
        int hb = (s00 ? 1 : 0) | (s01 ? 2 : 0) | (s10 ? 4 : 0) | (s11 ? 8 : 0);

        // ---- publish own row's hb(u) immediately (fire-and-forget byte) ----
        if (lane == 0)
            __hip_atomic_store(&slots[(size_t)u * NROW + row],
                               (uint8_t)(0xB0u | (uint32_t)hb),
                               __ATOMIC_RELAXED, __HIP_MEMORY_SCOPE_AGENT);

        // ---- resolve P[u-1]: own-row selfdec (88%) or global fallback ----
        int bst = 0;
        if (u >= 2) {
            if (rfl(selfdec)) {
                bst = 1;                   // own row spiked at u-2
            } else {
                for (;;) {
                    bool anyset, allp;
                    scan8(gv, kk, anyset, allp);
                    if (__any((int)anyset)) { bst = 1; break; }
                    if (__all((int)allp)) { bst = 0; break; }
                    __builtin_amdgcn_s_sleep(1);       // backoff (rare path)
                    gv = __hip_atomic_load(&gl[lane], __ATOMIC_RELAXED,
                                           __HIP_MEMORY_SCOPE_AGENT);
                }
            }
        }
        p3 = p2; p2 = bst;
        hb_m2 = hb_m1; hb_m1 = hb;

        // ---- collapse branch d=bst; record out bit; rebranch over c=P[u] ----
        bool sprv = bst ? psB : psA;                   // actual spike(u-1)
        bool sc0  = bst ? s10 : s00;                   // spike under c=0
        bool sc1  = bst ? s11 : s01;                   // spike under c=1
        float mc0 = bst ? m10 : m00;
        float mc1 = bst ? m11 : m01;

        if (u >= 1) {
            int v = u - 1;
            if ((v & 63) == lane) myb |= (sprv ? 1u : 0u) << (v >> 6);
        }

        memA = sc0 ? 0.0f : mc0;
        memB = sc1 ? 0.0f : mc1;
        bool eqNext = (sc0 == sc1) && (memA == memB);

        // collapse weights to the resolved d-branch (only if they differ)
        if (rfl(bst && !eq)) {
            #pragma unroll
            for (int j = 0; j < CPL; ++j) wA[j] = wB[j];
        }
        // wave-uniform branchy updates: only the taken path issues
        if (rfl(eqNext)) {
            if (rfl(sc0)) {                // potentiate (common path)
                #pragma unroll
                for (int j = 0; j < CPL; ++j) {
                    float pfj = (float)((cwd[j >> 2] >> ((j & 3) * 8 + 1)) & 3u);
                    wA[j] = fminf(wA[j] + pfj, 127.0f);
                }
            } else if (rfl(sprv)) {        // depress
                #pragma unroll
                for (int j = 0; j < CPL; ++j)
                    wA[j] = fmaxf(wA[j] - xf[j], 0.0f);
            }
            // wB stale; eq flag covers it
        } else {
            // divergent: build wB from pre-update wA base (c=1 path)
            if (rfl(sc1)) {
                #pragma unroll
                for (int j = 0; j < CPL; ++j) {
                    float pfj = (float)((cwd[j >> 2] >> ((j & 3) * 8 + 1)) & 3u);
                    wB[j] = fminf(wA[j] + pfj, 127.0f);
                }
            } else if (rfl(sprv)) {
                #pragma unroll
                for (int j = 0; j < CPL; ++j)
                    wB[j] = fmaxf(wA[j] - xf[j], 0.0f);
            } else {
                #pragma unroll
                for (int j = 0; j < CPL; ++j) wB[j] = wA[j];
            }
            if (rfl(sc0)) {                // c=0 path in place
                #pragma unroll
                for (int j = 0; j < CPL; ++j) {
                    float pfj = (float)((cwd[j >> 2] >> ((j & 3) * 8 + 1)) & 3u);
                    wA[j] = fminf(wA[j] + pfj, 127.0f);
                }
            } else if (rfl(sprv)) {
                #pragma unroll
                for (int j = 0; j < CPL; ++j)
                    wA[j] = fmaxf(wA[j] - xf[j], 0.0f);
            }
        }
        psA = sc0; psB = sc1; eq = eqNext;

        cw = cwn; cwn = cw2;
    }

    // ---- epilogue: resolve P[T-1], record last bit, write this row's out ----
    {
        const int kk = (p3 << 1) | p2;
        int cst;
        if (((hb_m2 >> kk) & 1) != 0) {
            cst = 1;                       // own row forced the OR
        } else {
            const unsigned long long* gl2 =
                (const unsigned long long*)(slots + (size_t)(T_STEPS - 2) * NROW);
            unsigned long long gv2;
            for (;;) {
                gv2 = __hip_atomic_load(&gl2[lane], __ATOMIC_RELAXED,
                                        __HIP_MEMORY_SCOPE_AGENT);
                bool anyset, allp;
                scan8(gv2, kk, anyset, allp);
                if (__any((int)anyset)) { cst = 1; break; }
                if (__all((int)allp)) { cst = 0; break; }
                __builtin_amdgcn_s_sleep(1);
            }
        }
        bool sr = cst ? psB : psA;
        {
            int v = T_STEPS - 1;
            if ((v & 63) == lane) myb |= (sr ? 1u : 0u) << (v >> 6);
        }
        // write this row's 1000 spike floats from the bit register
        #pragma unroll
        for (int b = 0; b < 16; ++b) {
            int s = b * 64 + lane;
            if (s < T_STEPS)
                out[(size_t)s * COUT + row] = (float)((myb >> b) & 1u);
        }
    }
}

extern "C" void kernel_launch(void* const* d_in, const int* in_sizes, int n_in,
                              void* d_out, int out_size, void* d_ws, size_t ws_size,
                              hipStream_t stream) {
    const int*   x      = (const int*)d_in[0];     // (T,1,CIN) int32
    const float* weight = (const float*)d_in[1];   // (COUT,CIN) f32
    float* out = (float*)d_out;                    // (T,1,COUT) f32

    uint8_t* slots = (uint8_t*)d_ws;
    uint8_t* code  = (uint8_t*)d_ws + CODE_OFFSET;

    int prep_threads = T_STEPS * 64;
    prep_kernel<<<(prep_threads + 255) / 256, 256, 0, stream>>>(x, code,
                                                                (uint2*)slots);
    snn_kernel<<<128, 256, 0, stream>>>(weight, code, slots, out);
}